// Round 3
// baseline (843.393 us; speedup 1.0000x reference)
//
#include <hip/hip_runtime.h>
#include <hip/hip_bf16.h>

#define N_NODES 100000
#define N_EDGES 3200000
#define D 128
#define CHUNK 1024
#define NBLK 98      // ceil(100000/1024)
#define GEMM_T 8     // nodes per gemm block

// ---- degree count over dst ----
__global__ void count_kernel(const int* __restrict__ ei, int* __restrict__ cnt) {
    int e = blockIdx.x * 256 + threadIdx.x;
    int d = ei[N_EDGES + e];
    atomicAdd(&cnt[d], 1);
}

// ---- deg^{-1/2} with self-loop (+1) ----
__global__ void dinv_kernel(const int* __restrict__ cnt, float* __restrict__ dinv) {
    int i = blockIdx.x * 256 + threadIdx.x;
    if (i < N_NODES) dinv[i] = rsqrtf((float)(cnt[i] + 1));
}

// ---- scan pass A: per-chunk sums ----
__global__ void scanA(const int* __restrict__ cnt, int* __restrict__ partial) {
    __shared__ int ls[4];
    int b = blockIdx.x, t = threadIdx.x;
    int base = b * CHUNK + t * 4;
    int s = 0;
#pragma unroll
    for (int k = 0; k < 4; k++) { int i = base + k; if (i < N_NODES) s += cnt[i]; }
    for (int off = 32; off; off >>= 1) s += __shfl_down(s, off, 64);
    if ((t & 63) == 0) ls[t >> 6] = s;
    __syncthreads();
    if (t == 0) partial[b] = ls[0] + ls[1] + ls[2] + ls[3];
}

// ---- scan pass B: exclusive scan of chunk sums (single block) ----
__global__ void scanB(int* __restrict__ partial) {
    __shared__ int s[128];
    int t = threadIdx.x;
    int v = (t < NBLK) ? partial[t] : 0;
    s[t] = v; __syncthreads();
    for (int off = 1; off < 128; off <<= 1) {
        int u = (t >= off) ? s[t - off] : 0;
        __syncthreads();
        s[t] += u;
        __syncthreads();
    }
    if (t < NBLK) partial[t] = s[t] - v;  // exclusive
}

// ---- scan pass C: per-element exclusive offsets ----
__global__ void scanC(const int* __restrict__ cnt, const int* __restrict__ partial,
                      int* __restrict__ offs) {
    __shared__ int s[256];
    int b = blockIdx.x, t = threadIdx.x;
    int base = b * CHUNK + t * 4;
    int v[4]; int tsum = 0;
#pragma unroll
    for (int k = 0; k < 4; k++) { int i = base + k; v[k] = (i < N_NODES) ? cnt[i] : 0; tsum += v[k]; }
    s[t] = tsum; __syncthreads();
    for (int off = 1; off < 256; off <<= 1) {
        int u = (t >= off) ? s[t - off] : 0;
        __syncthreads();
        s[t] += u;
        __syncthreads();
    }
    int run = partial[b] + s[t] - tsum;
#pragma unroll
    for (int k = 0; k < 4; k++) {
        int i = base + k;
        if (i < N_NODES) offs[i] = run;
        run += v[k];
    }
}

// ---- counting-sort scatter: bucket src by dst.
// offs doubles as cursor: after this kernel offs[n] = segment END.
__global__ void scatter_kernel(const int* __restrict__ ei, int* __restrict__ offs,
                               int* __restrict__ sorted_src) {
    int e = blockIdx.x * 256 + threadIdx.x;
    int s = ei[e];
    int d = ei[N_EDGES + e];
    int p = atomicAdd(&offs[d], 1);
    sorted_src[p] = s;
}

// ---- aggregate over X (before linear): agg[n] = dinv[n] * (dinv[n]*x[n] + sum dinv[s]*x[s]) ----
// agg lives in d_out (fp32). One block per node, thread = feature dim.
__global__ void aggregate_x_kernel(const float* __restrict__ x, const float* __restrict__ dinv,
                                   const int* __restrict__ offs, const int* __restrict__ cnt,
                                   const int* __restrict__ sorted_src,
                                   float* __restrict__ agg) {
    int n = blockIdx.x;
    int t = threadIdx.x;  // 0..127
    float dn = dinv[n];
    float acc = dn * x[(size_t)n * D + t];  // self-loop term
    int c = cnt[n];
    int beg = offs[n] - c;
    int i = 0;
    for (; i + 4 <= c; i += 4) {
        int s0 = sorted_src[beg + i];
        int s1 = sorted_src[beg + i + 1];
        int s2 = sorted_src[beg + i + 2];
        int s3 = sorted_src[beg + i + 3];
        float w0 = dinv[s0], w1 = dinv[s1], w2 = dinv[s2], w3 = dinv[s3];
        acc += w0 * x[(size_t)s0 * D + t];
        acc += w1 * x[(size_t)s1 * D + t];
        acc += w2 * x[(size_t)s2 * D + t];
        acc += w3 * x[(size_t)s3 * D + t];
    }
    for (; i < c; ++i) {
        int s = sorted_src[beg + i];
        acc += dinv[s] * x[(size_t)s * D + t];
    }
    agg[(size_t)n * D + t] = acc * dn;
}

// ---- in-place per-row GEMM: out[n] = agg[n] @ W^T + bias, agg==out rows.
// Block handles GEMM_T nodes; agg rows staged in LDS before overwrite.
__global__ void gemm_inplace_kernel(const float* __restrict__ w, const float* __restrict__ bias,
                                    float* __restrict__ out) {
    __shared__ float rows[GEMM_T][D];
    int b = blockIdx.x, t = threadIdx.x;  // t = 0..127 = output dim j
    int n0 = b * GEMM_T;
#pragma unroll
    for (int r = 0; r < GEMM_T; ++r) rows[r][t] = out[(size_t)(n0 + r) * D + t];
    __syncthreads();
    float acc[GEMM_T];
#pragma unroll
    for (int r = 0; r < GEMM_T; ++r) acc[r] = 0.f;
    const float4* w4 = (const float4*)(w + (size_t)t * D);
#pragma unroll
    for (int k4 = 0; k4 < D / 4; ++k4) {
        float4 wv = w4[k4];
        int k = k4 * 4;
#pragma unroll
        for (int r = 0; r < GEMM_T; ++r) {
            acc[r] += rows[r][k] * wv.x + rows[r][k + 1] * wv.y
                    + rows[r][k + 2] * wv.z + rows[r][k + 3] * wv.w;
        }
    }
    float bb = bias[t];
#pragma unroll
    for (int r = 0; r < GEMM_T; ++r) out[(size_t)(n0 + r) * D + t] = acc[r] + bb;
    // second tuple output: scalar 0
    if (b == 0 && t == 0) out[(size_t)N_NODES * D] = 0.f;
}

extern "C" void kernel_launch(void* const* d_in, const int* in_sizes, int n_in,
                              void* d_out, int out_size, void* d_ws, size_t ws_size,
                              hipStream_t stream) {
    const float* x = (const float*)d_in[0];
    const int* ei = (const int*)d_in[1];
    const float* w = (const float*)d_in[2];
    const float* bias = (const float*)d_in[3];
    float* out = (float*)d_out;

    char* ws = (char*)d_ws;
    size_t o = 0;
    auto alloc = [&](size_t bytes) -> char* {
        char* p = ws + o;
        o = (o + bytes + 511) & ~(size_t)511;
        return p;
    };
    // total ws footprint: ~14.1 MB
    int* sorted = (int*)alloc((size_t)N_EDGES * 4);     // 12.8 MB
    int* cnt = (int*)alloc((size_t)N_NODES * 4);        // 0.4 MB
    int* offs = (int*)alloc((size_t)N_NODES * 4);       // 0.4 MB
    float* dinv = (float*)alloc((size_t)N_NODES * 4);   // 0.4 MB
    int* partial = (int*)alloc(128 * 4);

    hipMemsetAsync(cnt, 0, (size_t)N_NODES * 4, stream);

    count_kernel<<<N_EDGES / 256, 256, 0, stream>>>(ei, cnt);
    dinv_kernel<<<(N_NODES + 255) / 256, 256, 0, stream>>>(cnt, dinv);
    scanA<<<NBLK, 256, 0, stream>>>(cnt, partial);
    scanB<<<1, 128, 0, stream>>>(partial);
    scanC<<<NBLK, 256, 0, stream>>>(cnt, partial, offs);
    scatter_kernel<<<N_EDGES / 256, 256, 0, stream>>>(ei, offs, sorted);
    aggregate_x_kernel<<<N_NODES, 128, 0, stream>>>(x, dinv, offs, cnt, sorted, out);
    gemm_inplace_kernel<<<N_NODES / GEMM_T, 128, 0, stream>>>(w, bias, out);
}